// Round 2
// baseline (480.235 us; speedup 1.0000x reference)
//
#include <hip/hip_runtime.h>
#include <hip/hip_bf16.h>

// SimpleMHA fused pipeline, bf16 MFMA compute, fp32 accumulate.
// B=4, S=2048, D=1024 (single head, scale = 1/32 exactly).

typedef __attribute__((ext_vector_type(8))) __bf16 bf16x8;
typedef __attribute__((ext_vector_type(4))) float f32x4;
typedef __attribute__((ext_vector_type(8))) unsigned short u16x8;
typedef __attribute__((ext_vector_type(4))) float float4v;

static __device__ __forceinline__ unsigned short f2b(float f) {
  // round-to-nearest-even f32 -> bf16 bits
  unsigned int u = __float_as_uint(f);
  u += 0x7fffu + ((u >> 16) & 1u);
  return (unsigned short)(u >> 16);
}
static __device__ __forceinline__ float b2f(unsigned short b) {
  return __uint_as_float(((unsigned int)b) << 16);
}

__global__ __launch_bounds__(256) void cvt_f32_bf16(const float* __restrict__ in,
                                                    unsigned short* __restrict__ out,
                                                    long long n) {
  long long i = ((long long)blockIdx.x * 256 + threadIdx.x) * 8;
  if (i + 8 > n) return;  // n is a multiple of 8 for all our arrays
  float4v a = *(const float4v*)(in + i);
  float4v b = *(const float4v*)(in + i + 4);
  u16x8 o;
  o[0] = f2b(a[0]); o[1] = f2b(a[1]); o[2] = f2b(a[2]); o[3] = f2b(a[3]);
  o[4] = f2b(b[0]); o[5] = f2b(b[1]); o[6] = f2b(b[2]); o[7] = f2b(b[3]);
  *(u16x8*)(out + i) = o;
}

// C = alpha * (A @ B + bias), A: [M,K] bf16 row-major.
// BT=0: B is [K,N] row-major (ldb = N). BT=1: B is [N,K] row-major (ldb = K), i.e. C = A @ B^T.
// C written as bf16 bits (c_is_bf16) or f32. Optional causal tile skip (needs BM==BN).
template <int BT>
__global__ __launch_bounds__(256) void gemm_bf16(
    const unsigned short* __restrict__ A, const unsigned short* __restrict__ B,
    const float* __restrict__ bias, void* __restrict__ C,
    int M, int N, int K, int lda, int ldb, int ldc,
    long long strideA, long long strideB, long long strideC,
    float alpha, int c_is_bf16, int causal) {
  constexpr int BM = 128, BN = 128, BK = 64;
  if (causal && blockIdx.x > blockIdx.y) return;  // tile fully above diagonal

  __shared__ unsigned short sA[BM][BK];   // A tile, k-contiguous rows
  __shared__ unsigned short sBt[BN][BK];  // B tile stored as [n][k] (canonical T)

  const int tid = threadIdx.x;
  const int bz = blockIdx.z;
  const unsigned short* Ab = A + (long long)bz * strideA;
  const unsigned short* Bb = B + (long long)bz * strideB;
  const int brow = blockIdx.y * BM;
  const int bcol = blockIdx.x * BN;
  const int w = tid >> 6, lane = tid & 63;
  const int wr = (w >> 1) * 64, wc = (w & 1) * 64;  // 2x2 wave grid, 64x64 each
  const int lr = lane & 15, lk = lane >> 4;

  f32x4 acc[4][4];
#pragma unroll
  for (int i = 0; i < 4; ++i)
#pragma unroll
    for (int n = 0; n < 4; ++n) acc[i][n] = (f32x4){0.f, 0.f, 0.f, 0.f};

  for (int kb = 0; kb < K; kb += BK) {
    __syncthreads();
    // stage A: 128 rows x 64 k, 16B per thread-slot, 1024 slots
#pragma unroll
    for (int it = 0; it < 4; ++it) {
      int s = tid + it * 256;
      int kg = s & 7, row = s >> 3;
      *(u16x8*)&sA[row][kg * 8] =
          *(const u16x8*)(Ab + (long long)(brow + row) * lda + kb + kg * 8);
    }
    if (BT) {
      // B^T input: same shape as A tile, direct 16B copies
#pragma unroll
      for (int it = 0; it < 4; ++it) {
        int s = tid + it * 256;
        int kg = s & 7, row = s >> 3;
        *(u16x8*)&sBt[row][kg * 8] =
            *(const u16x8*)(Bb + (long long)(bcol + row) * ldb + kb + kg * 8);
      }
    } else {
      // B [K,N] input: transpose through registers (8 x 2B strided global reads,
      // coalesced across lanes; one 16B LDS write)
#pragma unroll
      for (int it = 0; it < 4; ++it) {
        int s = tid + it * 256;
        int col = s & 127, kg = s >> 7;
        u16x8 v;
#pragma unroll
        for (int j = 0; j < 8; ++j)
          v[j] = Bb[(long long)(kb + kg * 8 + j) * ldb + bcol + col];
        *(u16x8*)&sBt[col][kg * 8] = v;
      }
    }
    __syncthreads();
#pragma unroll
    for (int kk = 0; kk < BK; kk += 32) {
      const int k0 = kk + lk * 8;
      bf16x8 af[4], bfr[4];
#pragma unroll
      for (int i = 0; i < 4; ++i)
        af[i] = *(const bf16x8*)&sA[wr + i * 16 + lr][k0];
#pragma unroll
      for (int n = 0; n < 4; ++n)
        bfr[n] = *(const bf16x8*)&sBt[wc + n * 16 + lr][k0];
#pragma unroll
      for (int i = 0; i < 4; ++i)
#pragma unroll
        for (int n = 0; n < 4; ++n)
          acc[i][n] = __builtin_amdgcn_mfma_f32_16x16x32_bf16(af[i], bfr[n], acc[i][n], 0, 0, 0);
    }
  }

  // epilogue: C/D layout col=lane&15, row=(lane>>4)*4+reg (m89-verified)
  long long cbase = (long long)bz * strideC;
#pragma unroll
  for (int i = 0; i < 4; ++i) {
    int row = brow + wr + i * 16 + lk * 4;
#pragma unroll
    for (int n = 0; n < 4; ++n) {
      int col = bcol + wc + n * 16 + lr;
      float bv = bias ? bias[col] : 0.0f;
#pragma unroll
      for (int r = 0; r < 4; ++r) {
        float v = (acc[i][n][r] + bv) * alpha;
        long long idx = cbase + (long long)(row + r) * ldc + col;
        if (c_is_bf16)
          ((unsigned short*)C)[idx] = f2b(v);
        else
          ((float*)C)[idx] = v;
      }
    }
  }
}

// In-place causal row softmax over bf16 scores. One 256-thread block per row.
// Writes exact zeros for masked (col > row) entries so the PV GEMM can run dense.
__global__ __launch_bounds__(256) void softmax_causal(unsigned short* __restrict__ S, int n) {
  const int r = blockIdx.x, b = blockIdx.y;
  unsigned short* row = S + ((long long)b * n + r) * (long long)n;
  const int L = r + 1;
  const int tid = threadIdx.x;
  __shared__ float red[4];

  float m = -3.0e38f;
  for (int i = tid; i < L; i += 256) m = fmaxf(m, b2f(row[i]));
#pragma unroll
  for (int o = 1; o < 64; o <<= 1) m = fmaxf(m, __shfl_xor(m, o, 64));
  if ((tid & 63) == 0) red[tid >> 6] = m;
  __syncthreads();
  m = fmaxf(fmaxf(red[0], red[1]), fmaxf(red[2], red[3]));
  __syncthreads();

  float s = 0.0f;
  for (int i = tid; i < L; i += 256) s += __expf(b2f(row[i]) - m);
#pragma unroll
  for (int o = 1; o < 64; o <<= 1) s += __shfl_xor(s, o, 64);
  if ((tid & 63) == 0) red[tid >> 6] = s;
  __syncthreads();
  s = red[0] + red[1] + red[2] + red[3];
  float inv = 1.0f / s;

  for (int i = tid; i < n; i += 256) {
    unsigned short o16 = 0;
    if (i < L) o16 = f2b(__expf(b2f(row[i]) - m) * inv);
    row[i] = o16;
  }
}

extern "C" void kernel_launch(void* const* d_in, const int* in_sizes, int n_in,
                              void* d_out, int out_size, void* d_ws, size_t ws_size,
                              hipStream_t stream) {
  const float* x  = (const float*)d_in[0];
  const float* Wq = (const float*)d_in[1];
  const float* bq = (const float*)d_in[2];
  const float* Wk = (const float*)d_in[3];
  const float* bk = (const float*)d_in[4];
  const float* Wv = (const float*)d_in[5];
  const float* bv = (const float*)d_in[6];
  const float* Wo = (const float*)d_in[7];
  const float* bo = (const float*)d_in[8];

  const int B = 4, S = 2048, D = 1024;
  const long long MS = (long long)B * S;  // 8192 rows

  char* p = (char*)d_ws;
  unsigned short* xb  = (unsigned short*)p; p += MS * D * 2;           // 16.8 MB
  unsigned short* Wqb = (unsigned short*)p; p += (long long)D * D * 2; // 2.1 MB
  unsigned short* Wkb = (unsigned short*)p; p += (long long)D * D * 2;
  unsigned short* Wvb = (unsigned short*)p; p += (long long)D * D * 2;
  unsigned short* Wob = (unsigned short*)p; p += (long long)D * D * 2;
  unsigned short* Qp  = (unsigned short*)p; p += MS * D * 2;           // Q * 1/32
  unsigned short* Kc  = (unsigned short*)p; p += MS * D * 2;
  unsigned short* Vc  = (unsigned short*)p; p += MS * D * 2;
  unsigned short* Sm  = (unsigned short*)p; p += (long long)B * S * S * 2;  // 33.6 MB
  unsigned short* At  = (unsigned short*)p; p += MS * D * 2;
  // total ~126 MB of d_ws

  dim3 blk(256);

  // f32 -> bf16 conversions
  cvt_f32_bf16<<<dim3(4096), blk, 0, stream>>>(x, xb, MS * D);
  cvt_f32_bf16<<<dim3(512), blk, 0, stream>>>(Wq, Wqb, (long long)D * D);
  cvt_f32_bf16<<<dim3(512), blk, 0, stream>>>(Wk, Wkb, (long long)D * D);
  cvt_f32_bf16<<<dim3(512), blk, 0, stream>>>(Wv, Wvb, (long long)D * D);
  cvt_f32_bf16<<<dim3(512), blk, 0, stream>>>(Wo, Wob, (long long)D * D);

  // QKV projections: [8192,1024] @ [1024,1024] + bias. Scale 1/32 folded into Q.
  gemm_bf16<0><<<dim3(D / 128, MS / 128, 1), blk, 0, stream>>>(
      xb, Wqb, bq, Qp, (int)MS, D, D, D, D, D, 0, 0, 0, 0.03125f, 1, 0);
  gemm_bf16<0><<<dim3(D / 128, MS / 128, 1), blk, 0, stream>>>(
      xb, Wkb, bk, Kc, (int)MS, D, D, D, D, D, 0, 0, 0, 1.0f, 1, 0);
  gemm_bf16<0><<<dim3(D / 128, MS / 128, 1), blk, 0, stream>>>(
      xb, Wvb, bv, Vc, (int)MS, D, D, D, D, D, 0, 0, 0, 1.0f, 1, 0);

  // Scores: S[b] = Q'[b] @ K[b]^T, causal tiles skipped above diagonal.
  gemm_bf16<1><<<dim3(S / 128, S / 128, B), blk, 0, stream>>>(
      Qp, Kc, nullptr, Sm, S, S, D, D, D, S,
      (long long)S * D, (long long)S * D, (long long)S * S, 1.0f, 1, 1);

  // Causal softmax in place (zeros masked region for dense PV).
  softmax_causal<<<dim3(S, B), blk, 0, stream>>>(Sm, S);

  // attn = P @ V
  gemm_bf16<0><<<dim3(D / 128, S / 128, B), blk, 0, stream>>>(
      Sm, Vc, nullptr, At, S, D, S, S, D, D,
      (long long)S * S, (long long)S * D, (long long)S * D, 1.0f, 1, 0);

  // out = attn @ Wo + bo (f32 output)
  gemm_bf16<0><<<dim3(D / 128, MS / 128, 1), blk, 0, stream>>>(
      At, Wob, bo, d_out, (int)MS, D, D, D, D, D, 0, 0, 0, 1.0f, 0, 0);
}

// Round 3
// 388.558 us; speedup vs baseline: 1.2359x; 1.2359x over previous
//
#include <hip/hip_runtime.h>
#include <hip/hip_bf16.h>

// SimpleMHA, all-TN bf16 MFMA GEMMs with global_load_lds staging (m97 structure).
// B=4, S=2048, D=1024, scale 1/32 applied in the score GEMM epilogue.

typedef __attribute__((ext_vector_type(8))) __bf16 bf16x8;
typedef __attribute__((ext_vector_type(4))) float f32x4;
typedef __attribute__((ext_vector_type(8))) unsigned short u16x8;
typedef __attribute__((ext_vector_type(4))) float float4v;
typedef long long ll;

static __device__ __forceinline__ unsigned short f2b(float f) {
  unsigned int u = __float_as_uint(f);
  u += 0x7fffu + ((u >> 16) & 1u);
  return (unsigned short)(u >> 16);
}
static __device__ __forceinline__ float b2f(unsigned short b) {
  return __uint_as_float(((unsigned int)b) << 16);
}

static __device__ __forceinline__ void gload16(const unsigned short* g, unsigned short* l) {
  // 16B direct global->LDS. LDS dest = wave-uniform base + lane*16 (HW rule).
  __builtin_amdgcn_global_load_lds(
      (const __attribute__((address_space(1))) void*)g,
      (__attribute__((address_space(3))) void*)l, 16, 0, 0);
}

__global__ __launch_bounds__(256) void cvt_f32_bf16(const float* __restrict__ in,
                                                    unsigned short* __restrict__ out,
                                                    long long n) {
  long long i = ((long long)blockIdx.x * 256 + threadIdx.x) * 8;
  if (i + 8 > n) return;
  float4v a = *(const float4v*)(in + i);
  float4v b = *(const float4v*)(in + i + 4);
  u16x8 o;
  o[0] = f2b(a[0]); o[1] = f2b(a[1]); o[2] = f2b(a[2]); o[3] = f2b(a[3]);
  o[4] = f2b(b[0]); o[5] = f2b(b[1]); o[6] = f2b(b[2]); o[7] = f2b(b[3]);
  *(u16x8*)(out + i) = o;
}

// out[c][r] = bf16(in[r][c]) for n x n f32 input. Block (32,8), 32x32 tiles.
__global__ __launch_bounds__(256) void transpose_cvt(const float* __restrict__ in,
                                                     unsigned short* __restrict__ out, int n) {
  __shared__ float t[32][33];
  int bx = blockIdx.x * 32, by = blockIdx.y * 32;
  int tx = threadIdx.x, ty = threadIdx.y;
#pragma unroll
  for (int i = 0; i < 32; i += 8)
    t[ty + i][tx] = in[(ll)(by + ty + i) * n + bx + tx];
  __syncthreads();
#pragma unroll
  for (int i = 0; i < 32; i += 8)
    out[(ll)(bx + ty + i) * n + by + tx] = f2b(t[tx][ty + i]);
}

__global__ void concat2(const float* __restrict__ a, const float* __restrict__ b,
                        float* __restrict__ o, int n) {
  int i = blockIdx.x * 256 + threadIdx.x;
  if (i < n) { o[i] = a[i]; o[i + n] = b[i]; }
}

// C = alpha*(A @ B^T + bias). A:[M,K] lda, B:[N,K] ldb, both bf16 k-contiguous.
// 128x128 tile, BK=64, 4 waves (2x2 of 64x64), global_load_lds staging.
// CAUSAL: 0 dense; 1 scores (skip tiles with bcol>brow); 2 PV (Keff = brow+128).
template <int CAUSAL>
__global__ __launch_bounds__(256) void gemm_tn(
    const unsigned short* __restrict__ A, const unsigned short* __restrict__ B,
    const float* __restrict__ bias, void* __restrict__ C,
    int K, int lda, int ldb, int ldc,
    ll strideA, ll strideB, ll strideC,
    float alpha, int c_is_bf16, int bias_row) {
  if (CAUSAL == 1 && blockIdx.x > blockIdx.y) return;

  __shared__ unsigned short sA[128][64];
  __shared__ unsigned short sB[128][64];

  const int tid = threadIdx.x;
  const int w = tid >> 6, lane = tid & 63;
  const int bz = blockIdx.z;
  const unsigned short* Ab = A + (ll)bz * strideA;
  const unsigned short* Bb = B + (ll)bz * strideB;
  const int brow = blockIdx.y * 128, bcol = blockIdx.x * 128;
  const int wr = (w >> 1) * 64, wc = (w & 1) * 64;
  const int lr = lane & 15, lk = lane >> 4;

  const int Keff = (CAUSAL == 2) ? (brow + 128) : K;

  f32x4 acc[4][4];
#pragma unroll
  for (int i = 0; i < 4; ++i)
#pragma unroll
    for (int n = 0; n < 4; ++n) acc[i][n] = (f32x4){0.f, 0.f, 0.f, 0.f};

  for (int kb = 0; kb < Keff; kb += 64) {
    __syncthreads();
    // 16KB tile = 16 chunks of 1KB; wave w handles chunks {it*4+w}.
    // LDS linear: byte slot*16 where slot = chunk*64+lane -> row=slot>>3, kg=slot&7.
#pragma unroll
    for (int it = 0; it < 4; ++it) {
      const int chunk = it * 4 + w;
      const int slot = chunk * 64 + lane;
      const int row = slot >> 3, kg = slot & 7;
      gload16(Ab + (ll)(brow + row) * lda + kb + kg * 8, &sA[0][0] + chunk * 512);
      gload16(Bb + (ll)(bcol + row) * ldb + kb + kg * 8, &sB[0][0] + chunk * 512);
    }
    __syncthreads();  // compiler emits vmcnt(0) drain here
#pragma unroll
    for (int kk = 0; kk < 64; kk += 32) {
      const int k0 = kk + lk * 8;
      bf16x8 af[4], bfr[4];
#pragma unroll
      for (int i = 0; i < 4; ++i) af[i] = *(const bf16x8*)&sA[wr + i * 16 + lr][k0];
#pragma unroll
      for (int n = 0; n < 4; ++n) bfr[n] = *(const bf16x8*)&sB[wc + n * 16 + lr][k0];
#pragma unroll
      for (int i = 0; i < 4; ++i)
#pragma unroll
        for (int n = 0; n < 4; ++n)
          acc[i][n] = __builtin_amdgcn_mfma_f32_16x16x32_bf16(af[i], bfr[n], acc[i][n], 0, 0, 0);
    }
  }

  // C/D layout: col=lane&15, row=(lane>>4)*4+reg (m89-verified)
  ll cbase = (ll)bz * strideC;
#pragma unroll
  for (int i = 0; i < 4; ++i) {
    int row = brow + wr + i * 16 + lk * 4;
#pragma unroll
    for (int n = 0; n < 4; ++n) {
      int col = bcol + wc + n * 16 + lr;
#pragma unroll
      for (int r = 0; r < 4; ++r) {
        float bvv = bias ? (bias_row ? bias[row + r] : bias[col]) : 0.0f;
        float v = (acc[i][n][r] + bvv) * alpha;
        ll idx = cbase + (ll)(row + r) * ldc + col;
        if (c_is_bf16) ((unsigned short*)C)[idx] = f2b(v);
        else ((float*)C)[idx] = v;
      }
    }
  }
}

// One-pass causal softmax for rows of exactly 2048 bf16. One block per row;
// each thread owns one u16x8. Masked cols written as exact 0.
__global__ __launch_bounds__(256) void softmax_row2048(unsigned short* __restrict__ S) {
  const int r = blockIdx.x, b = blockIdx.y;
  unsigned short* row = S + ((ll)b * 2048 + r) * 2048;
  const int tid = threadIdx.x;
  const int i0 = tid * 8;
  __shared__ float red[4];

  u16x8 v = *(const u16x8*)(row + i0);
  float f[8];
  float m = -3.0e38f;
#pragma unroll
  for (int j = 0; j < 8; ++j) {
    f[j] = (i0 + j <= r) ? b2f(v[j]) : -3.0e38f;
    m = fmaxf(m, f[j]);
  }
#pragma unroll
  for (int o = 1; o < 64; o <<= 1) m = fmaxf(m, __shfl_xor(m, o, 64));
  if ((tid & 63) == 0) red[tid >> 6] = m;
  __syncthreads();
  m = fmaxf(fmaxf(red[0], red[1]), fmaxf(red[2], red[3]));
  __syncthreads();

  float e[8];
  float s = 0.0f;
#pragma unroll
  for (int j = 0; j < 8; ++j) {
    e[j] = (i0 + j <= r) ? __expf(f[j] - m) : 0.0f;
    s += e[j];
  }
#pragma unroll
  for (int o = 1; o < 64; o <<= 1) s += __shfl_xor(s, o, 64);
  if ((tid & 63) == 0) red[tid >> 6] = s;
  __syncthreads();
  s = red[0] + red[1] + red[2] + red[3];
  float inv = 1.0f / s;
  u16x8 o8;
#pragma unroll
  for (int j = 0; j < 8; ++j) o8[j] = f2b(e[j] * inv);
  *(u16x8*)(row + i0) = o8;
}

extern "C" void kernel_launch(void* const* d_in, const int* in_sizes, int n_in,
                              void* d_out, int out_size, void* d_ws, size_t ws_size,
                              hipStream_t stream) {
  const float* x  = (const float*)d_in[0];
  const float* Wq = (const float*)d_in[1];
  const float* bq = (const float*)d_in[2];
  const float* Wk = (const float*)d_in[3];
  const float* bk = (const float*)d_in[4];
  const float* Wv = (const float*)d_in[5];
  const float* bv = (const float*)d_in[6];
  const float* Wo = (const float*)d_in[7];
  const float* bo = (const float*)d_in[8];

  const int B = 4, S = 2048, D = 1024;
  const ll MS = (ll)B * S;  // 8192

  char* p = (char*)d_ws;
  unsigned short* xb   = (unsigned short*)p; p += MS * D * 2;              // 16.8 MB
  unsigned short* Wqkt = (unsigned short*)p; p += (ll)2 * D * D * 2;       // 4.2 MB: [Wq^T; Wk^T]
  unsigned short* Wvt  = (unsigned short*)p; p += (ll)D * D * 2;           // Wv^T
  unsigned short* Wot  = (unsigned short*)p; p += (ll)D * D * 2;           // Wo^T
  float*          bqkc = (float*)p;          p += 2 * D * 4;               // [bq; bk]
  unsigned short* QKc  = (unsigned short*)p; p += MS * 2 * D * 2;          // 33.6 MB: [Q | K]
  unsigned short* Vt   = (unsigned short*)p; p += (ll)D * MS * 2;          // 16.8 MB: V^T [D, MS]
  unsigned short* Sm   = (unsigned short*)p; p += (ll)B * S * S * 2;       // 33.6 MB
  unsigned short* At   = (unsigned short*)p; p += MS * D * 2;              // 16.8 MB

  dim3 blk(256);
  dim3 tblk(32, 8);

  cvt_f32_bf16<<<dim3(4096), blk, 0, stream>>>(x, xb, MS * D);
  transpose_cvt<<<dim3(32, 32), tblk, 0, stream>>>(Wq, Wqkt, D);
  transpose_cvt<<<dim3(32, 32), tblk, 0, stream>>>(Wk, Wqkt + (ll)D * D, D);
  transpose_cvt<<<dim3(32, 32), tblk, 0, stream>>>(Wv, Wvt, D);
  transpose_cvt<<<dim3(32, 32), tblk, 0, stream>>>(Wo, Wot, D);
  concat2<<<dim3(4), blk, 0, stream>>>(bq, bk, bqkc, D);

  // Fused Q|K projection: C[8192, 2048] = x @ [Wq|Wk] + [bq|bk]
  gemm_tn<0><<<dim3(16, 64, 1), blk, 0, stream>>>(
      xb, Wqkt, bqkc, QKc, D, D, D, 2 * D, 0, 0, 0, 1.0f, 1, 0);

  // V^T [1024, 8192] = Wv^T @ x^T + bv (row bias)
  gemm_tn<0><<<dim3(64, 8, 1), blk, 0, stream>>>(
      Wvt, xb, bv, Vt, D, D, D, (int)MS, 0, 0, 0, 1.0f, 1, 1);

  // Scores: Sm[b] = (Q_b @ K_b^T) / 32, upper tiles skipped
  gemm_tn<1><<<dim3(16, 16, 4), blk, 0, stream>>>(
      QKc, QKc + D, nullptr, Sm, D, 2 * D, 2 * D, S,
      (ll)S * 2 * D, (ll)S * 2 * D, (ll)S * S, 0.03125f, 1, 0);

  softmax_row2048<<<dim3(S, B), blk, 0, stream>>>(Sm);

  // PV: At[b] = P_b @ V_b, K-loop limited to brow+128 (causal zeros beyond)
  gemm_tn<2><<<dim3(8, 16, 4), blk, 0, stream>>>(
      Sm, Vt, nullptr, At, S, S, (int)MS, D,
      (ll)S * S, (ll)S, (ll)S * D, 1.0f, 1, 0);

  // out = At @ Wo + bo (f32)
  gemm_tn<0><<<dim3(8, 64, 1), blk, 0, stream>>>(
      At, Wot, bo, d_out, D, D, D, D, 0, 0, 0, 1.0f, 0, 0);
}

// Round 4
// 360.295 us; speedup vs baseline: 1.3329x; 1.0784x over previous
//
#include <hip/hip_runtime.h>
#include <hip/hip_bf16.h>

// SimpleMHA, all-TN bf16 MFMA GEMMs: 2-phase double-buffered global_load_lds
// staging + XOR bank-swizzle (pre-swizzled global source, swizzled ds_read).
// B=4, S=2048, D=1024, scale 1/32 applied in the score GEMM epilogue.

typedef __attribute__((ext_vector_type(8))) __bf16 bf16x8;
typedef __attribute__((ext_vector_type(4))) float f32x4;
typedef __attribute__((ext_vector_type(8))) unsigned short u16x8;
typedef __attribute__((ext_vector_type(4))) float float4v;
typedef long long ll;

static __device__ __forceinline__ unsigned short f2b(float f) {
  unsigned int u = __float_as_uint(f);
  u += 0x7fffu + ((u >> 16) & 1u);
  return (unsigned short)(u >> 16);
}
static __device__ __forceinline__ float b2f(unsigned short b) {
  return __uint_as_float(((unsigned int)b) << 16);
}

static __device__ __forceinline__ void gload16(const unsigned short* g, unsigned short* l) {
  // 16B direct global->LDS. LDS dest = wave-uniform base + lane*16 (HW rule).
  __builtin_amdgcn_global_load_lds(
      (const __attribute__((address_space(1))) void*)g,
      (__attribute__((address_space(3))) void*)l, 16, 0, 0);
}

__global__ __launch_bounds__(256) void cvt_f32_bf16(const float* __restrict__ in,
                                                    unsigned short* __restrict__ out,
                                                    long long n) {
  long long i = ((long long)blockIdx.x * 256 + threadIdx.x) * 8;
  if (i + 8 > n) return;
  float4v a = *(const float4v*)(in + i);
  float4v b = *(const float4v*)(in + i + 4);
  u16x8 o;
  o[0] = f2b(a[0]); o[1] = f2b(a[1]); o[2] = f2b(a[2]); o[3] = f2b(a[3]);
  o[4] = f2b(b[0]); o[5] = f2b(b[1]); o[6] = f2b(b[2]); o[7] = f2b(b[3]);
  *(u16x8*)(out + i) = o;
}

// out[c][r] = bf16(in[r][c]) for n x n f32 input. Block (32,8), 32x32 tiles.
__global__ __launch_bounds__(256) void transpose_cvt(const float* __restrict__ in,
                                                     unsigned short* __restrict__ out, int n) {
  __shared__ float t[32][33];
  int bx = blockIdx.x * 32, by = blockIdx.y * 32;
  int tx = threadIdx.x, ty = threadIdx.y;
#pragma unroll
  for (int i = 0; i < 32; i += 8)
    t[ty + i][tx] = in[(ll)(by + ty + i) * n + bx + tx];
  __syncthreads();
#pragma unroll
  for (int i = 0; i < 32; i += 8)
    out[(ll)(bx + ty + i) * n + by + tx] = f2b(t[tx][ty + i]);
}

__global__ void concat2(const float* __restrict__ a, const float* __restrict__ b,
                        float* __restrict__ o, int n) {
  int i = blockIdx.x * 256 + threadIdx.x;
  if (i < n) { o[i] = a[i]; o[i + n] = b[i]; }
}

// C = alpha*(A @ B^T + bias). A:[M,K] lda, B:[N,K] ldb, both bf16 k-contiguous.
// 128x128 tile, BK=64, 4 waves (2x2 of 64x64). 2-phase double-buffer:
// issue next tile's global_load_lds BEFORE current tile's ds_read+MFMA,
// one __syncthreads per K-step (drains vmcnt after MFMA -> latency hidden).
// LDS bank swizzle: 16B slot s holds global k-group s^(row&7); applied on the
// GLOBAL source address at stage time and on the ds_read address (involution).
// CAUSAL: 0 dense; 1 scores (skip tiles with bcol>brow); 2 PV (Keff = brow+128).
template <int CAUSAL>
__global__ __launch_bounds__(256, 2) void gemm_tn(
    const unsigned short* __restrict__ A, const unsigned short* __restrict__ B,
    const float* __restrict__ bias, void* __restrict__ C,
    int K, int lda, int ldb, int ldc,
    ll strideA, ll strideB, ll strideC,
    float alpha, int c_is_bf16, int bias_row) {
  if (CAUSAL == 1 && blockIdx.x > blockIdx.y) return;

  __shared__ unsigned short sA[2][128][64];  // 32 KB
  __shared__ unsigned short sB[2][128][64];  // 32 KB

  const int tid = threadIdx.x;
  const int w = tid >> 6, lane = tid & 63;
  const int bz = blockIdx.z;
  const unsigned short* Ab = A + (ll)bz * strideA;
  const unsigned short* Bb = B + (ll)bz * strideB;
  const int brow = blockIdx.y * 128, bcol = blockIdx.x * 128;
  const int wr = (w >> 1) * 64, wc = (w & 1) * 64;
  const int lr = lane & 15, lk = lane >> 4;

  const int Keff = (CAUSAL == 2) ? (brow + 128) : K;
  const int nt = Keff >> 6;

  f32x4 acc[4][4];
#pragma unroll
  for (int i = 0; i < 4; ++i)
#pragma unroll
    for (int n = 0; n < 4; ++n) acc[i][n] = (f32x4){0.f, 0.f, 0.f, 0.f};

  // Per-thread stage: 4 chunks of A + 4 of B. LDS dest linear (slot*16B);
  // global source column-group = slot_s ^ (row&7)  (bank swizzle).
  auto STAGE = [&](int buf, int kb) {
#pragma unroll
    for (int it = 0; it < 4; ++it) {
      const int chunk = it * 4 + w;
      const int slot = chunk * 64 + lane;
      const int row = slot >> 3;
      const int kg = (slot & 7) ^ (row & 7);
      gload16(Ab + (ll)(brow + row) * lda + kb + kg * 8, &sA[buf][0][0] + chunk * 512);
      gload16(Bb + (ll)(bcol + row) * ldb + kb + kg * 8, &sB[buf][0][0] + chunk * 512);
    }
  };

  auto COMPUTE = [&](int buf) {
#pragma unroll
    for (int kk = 0; kk < 64; kk += 32) {
      bf16x8 af[4], bfr[4];
      const int kgb = (kk >> 3) + lk;          // linear k-group for this lane
      const int sw = (kgb ^ (lr & 7)) * 8;     // swizzled element offset
#pragma unroll
      for (int i = 0; i < 4; ++i) af[i] = *(const bf16x8*)&sA[buf][wr + i * 16 + lr][sw];
#pragma unroll
      for (int n = 0; n < 4; ++n) bfr[n] = *(const bf16x8*)&sB[buf][wc + n * 16 + lr][sw];
#pragma unroll
      for (int i = 0; i < 4; ++i)
#pragma unroll
        for (int n = 0; n < 4; ++n)
          acc[i][n] = __builtin_amdgcn_mfma_f32_16x16x32_bf16(af[i], bfr[n], acc[i][n], 0, 0, 0);
    }
  };

  STAGE(0, 0);
  __syncthreads();  // vmcnt(0) drain + barrier: tile 0 ready
  int cur = 0;
  for (int t = 0; t < nt - 1; ++t) {
    STAGE(cur ^ 1, (t + 1) << 6);  // issue next tile's loads first
    COMPUTE(cur);                  // MFMA hides the load latency
    __syncthreads();               // drain + barrier: next tile ready
    cur ^= 1;
  }
  COMPUTE(cur);

  // C/D layout: col=lane&15, row=(lane>>4)*4+reg (m89-verified)
  ll cbase = (ll)bz * strideC;
#pragma unroll
  for (int i = 0; i < 4; ++i) {
    int row = brow + wr + i * 16 + lk * 4;
#pragma unroll
    for (int n = 0; n < 4; ++n) {
      int col = bcol + wc + n * 16 + lr;
#pragma unroll
      for (int r = 0; r < 4; ++r) {
        float bvv = bias ? (bias_row ? bias[row + r] : bias[col]) : 0.0f;
        float v = (acc[i][n][r] + bvv) * alpha;
        ll idx = cbase + (ll)(row + r) * ldc + col;
        if (c_is_bf16) ((unsigned short*)C)[idx] = f2b(v);
        else ((float*)C)[idx] = v;
      }
    }
  }
}

// One-pass causal softmax for rows of exactly 2048 bf16. One block per row;
// each thread owns one u16x8. Masked cols written as exact 0.
__global__ __launch_bounds__(256) void softmax_row2048(unsigned short* __restrict__ S) {
  const int r = blockIdx.x, b = blockIdx.y;
  unsigned short* row = S + ((ll)b * 2048 + r) * 2048;
  const int tid = threadIdx.x;
  const int i0 = tid * 8;
  __shared__ float red[4];

  u16x8 v = *(const u16x8*)(row + i0);
  float f[8];
  float m = -3.0e38f;
#pragma unroll
  for (int j = 0; j < 8; ++j) {
    f[j] = (i0 + j <= r) ? b2f(v[j]) : -3.0e38f;
    m = fmaxf(m, f[j]);
  }
#pragma unroll
  for (int o = 1; o < 64; o <<= 1) m = fmaxf(m, __shfl_xor(m, o, 64));
  if ((tid & 63) == 0) red[tid >> 6] = m;
  __syncthreads();
  m = fmaxf(fmaxf(red[0], red[1]), fmaxf(red[2], red[3]));
  __syncthreads();

  float e[8];
  float s = 0.0f;
#pragma unroll
  for (int j = 0; j < 8; ++j) {
    e[j] = (i0 + j <= r) ? __expf(f[j] - m) : 0.0f;
    s += e[j];
  }
#pragma unroll
  for (int o = 1; o < 64; o <<= 1) s += __shfl_xor(s, o, 64);
  if ((tid & 63) == 0) red[tid >> 6] = s;
  __syncthreads();
  s = red[0] + red[1] + red[2] + red[3];
  float inv = 1.0f / s;
  u16x8 o8;
#pragma unroll
  for (int j = 0; j < 8; ++j) o8[j] = f2b(e[j] * inv);
  *(u16x8*)(row + i0) = o8;
}

extern "C" void kernel_launch(void* const* d_in, const int* in_sizes, int n_in,
                              void* d_out, int out_size, void* d_ws, size_t ws_size,
                              hipStream_t stream) {
  const float* x  = (const float*)d_in[0];
  const float* Wq = (const float*)d_in[1];
  const float* bq = (const float*)d_in[2];
  const float* Wk = (const float*)d_in[3];
  const float* bk = (const float*)d_in[4];
  const float* Wv = (const float*)d_in[5];
  const float* bv = (const float*)d_in[6];
  const float* Wo = (const float*)d_in[7];
  const float* bo = (const float*)d_in[8];

  const int B = 4, S = 2048, D = 1024;
  const ll MS = (ll)B * S;  // 8192

  char* p = (char*)d_ws;
  unsigned short* xb   = (unsigned short*)p; p += MS * D * 2;              // 16.8 MB
  unsigned short* Wqkt = (unsigned short*)p; p += (ll)2 * D * D * 2;       // 4.2 MB: [Wq^T; Wk^T]
  unsigned short* Wvt  = (unsigned short*)p; p += (ll)D * D * 2;           // Wv^T
  unsigned short* Wot  = (unsigned short*)p; p += (ll)D * D * 2;           // Wo^T
  float*          bqkc = (float*)p;          p += 2 * D * 4;               // [bq; bk]
  unsigned short* QKc  = (unsigned short*)p; p += MS * 2 * D * 2;          // 33.6 MB: [Q | K]
  unsigned short* Vt   = (unsigned short*)p; p += (ll)D * MS * 2;          // 16.8 MB: V^T [D, MS]
  unsigned short* Sm   = (unsigned short*)p; p += (ll)B * S * S * 2;       // 33.6 MB
  unsigned short* At   = (unsigned short*)p; p += MS * D * 2;              // 16.8 MB

  dim3 blk(256);
  dim3 tblk(32, 8);

  cvt_f32_bf16<<<dim3(4096), blk, 0, stream>>>(x, xb, MS * D);
  transpose_cvt<<<dim3(32, 32), tblk, 0, stream>>>(Wq, Wqkt, D);
  transpose_cvt<<<dim3(32, 32), tblk, 0, stream>>>(Wk, Wqkt + (ll)D * D, D);
  transpose_cvt<<<dim3(32, 32), tblk, 0, stream>>>(Wv, Wvt, D);
  transpose_cvt<<<dim3(32, 32), tblk, 0, stream>>>(Wo, Wot, D);
  concat2<<<dim3(4), blk, 0, stream>>>(bq, bk, bqkc, D);

  // Fused Q|K projection: C[8192, 2048] = x @ [Wq|Wk] + [bq|bk]
  gemm_tn<0><<<dim3(16, 64, 1), blk, 0, stream>>>(
      xb, Wqkt, bqkc, QKc, D, D, D, 2 * D, 0, 0, 0, 1.0f, 1, 0);

  // V^T [1024, 8192] = Wv^T @ x^T + bv (row bias)
  gemm_tn<0><<<dim3(64, 8, 1), blk, 0, stream>>>(
      Wvt, xb, bv, Vt, D, D, D, (int)MS, 0, 0, 0, 1.0f, 1, 1);

  // Scores: Sm[b] = (Q_b @ K_b^T) / 32, upper tiles skipped
  gemm_tn<1><<<dim3(16, 16, 4), blk, 0, stream>>>(
      QKc, QKc + D, nullptr, Sm, D, 2 * D, 2 * D, S,
      (ll)S * 2 * D, (ll)S * 2 * D, (ll)S * S, 0.03125f, 1, 0);

  softmax_row2048<<<dim3(S, B), blk, 0, stream>>>(Sm);

  // PV: At[b] = P_b @ V_b, K-loop limited to brow+128 (causal zeros beyond)
  gemm_tn<2><<<dim3(8, 16, 4), blk, 0, stream>>>(
      Sm, Vt, nullptr, At, S, S, (int)MS, D,
      (ll)S * S, (ll)S, (ll)S * D, 1.0f, 1, 0);

  // out = At @ Wo + bo (f32)
  gemm_tn<0><<<dim3(8, 64, 1), blk, 0, stream>>>(
      At, Wot, bo, d_out, D, D, D, D, 0, 0, 0, 1.0f, 0, 0);
}